// Round 4
// baseline (284.727 us; speedup 1.0000x reference)
//
#include <hip/hip_runtime.h>
#include <cstdint>
#include <cstddef>

#define S_NUM 100000
#define T_NUM 20000
#define E_NUM 1000000

#define NB   1250     // buckets (T / GT)
#define GT   16       // targets per bucket
#define CAP  1280     // entries per bucket slot (mean 800, max ~950)
#define CH   4096     // edges per partition chunk
#define KB2  245      // partition blocks (= chunks)
#define SB   1024     // streaming blocks in k12'

typedef __bf16 bf16x8 __attribute__((ext_vector_type(8)));
typedef float f32x4 __attribute__((ext_vector_type(4)));

__device__ __forceinline__ unsigned short f2bf(float f) {
  unsigned int u = __float_as_uint(f);
  u += 0x7fffu + ((u >> 16) & 1u);   // round-to-nearest-even
  return (unsigned short)(u >> 16);
}
__device__ __forceinline__ unsigned int f2bf2(float lo, float hi) {
  return (unsigned int)f2bf(lo) | ((unsigned int)f2bf(hi) << 16);
}
__device__ __forceinline__ float bflo(unsigned int v) { return __uint_as_float(v << 16); }
__device__ __forceinline__ float bfhi(unsigned int v) { return __uint_as_float(v & 0xffff0000u); }

// R16-k0: EW = embed @ weight (f32, on device, 4 MFLOP), stored transposed
// bf16 fragment-contiguous: ewT[n][k] = bf16(EW[k][n]), n<128, k<256.
// Exploits linearity: mean(x[src]) @ W == mean(sf[src]/xn) @ (E@W), which
// removes the entire [100K,256]@[256,128] GEMM stage from the hot path.
// Also zeroes gcursor (replaces memset dispatch).
__launch_bounds__(256)
__global__ void k0_prep(const float* __restrict__ embed, const float* __restrict__ weight,
                        int* __restrict__ gcursor, unsigned short* __restrict__ ewT) {
  __shared__ float W[128][128];      // 65,536 B
  const int tid = threadIdx.x;
  const int b = blockIdx.x;          // 128 blocks
  for (int i = tid; i < 16384; i += 256)
    ((float*)W)[i] = weight[i];
  const int gidx = b * 256 + tid;
  if (gidx < 2048) gcursor[gidx] = 0;
  __syncthreads();
  const int r = tid >> 7;            // 0..1
  const int n = tid & 127;
  const int k = b * 2 + r;           // 0..255
  float acc = 0.f;
#pragma unroll 8
  for (int j = 0; j < 128; ++j)
    acc = fmaf(embed[(size_t)k * 128 + j], W[j][n], acc);
  ewT[(size_t)n * 256 + k] = f2bf(acc);
}

// K12': blocks [0,KB2) partition edges into NB buckets (unchanged);
// blocks [KB2, KB2+SB) stream sfb = bf16(sf/xn) -- pure BW, no GEMM.
__launch_bounds__(512)
__global__ void k12_fused(const float* __restrict__ sf, const float* __restrict__ xn,
                          unsigned short* __restrict__ sfb,
                          const int* __restrict__ src_idx, const int* __restrict__ dst_idx,
                          int* __restrict__ gcursor, unsigned int* __restrict__ ebuf) {
  __shared__ int part[2560];         // bcnt[1280] + gbase[1280]
  const int tid = threadIdx.x;

  if (blockIdx.x < KB2) {
    // ---- partition one CH-edge chunk into NB buckets ----
    int* bcnt  = part;
    int* gbase = part + 1280;
    const int e0 = blockIdx.x * CH;
    const int e1 = (e0 + CH < E_NUM) ? (e0 + CH) : E_NUM;
    for (int i = tid; i < NB; i += 512) bcnt[i] = 0;
    __syncthreads();
    for (int e = e0 + tid; e < e1; e += 512)
      atomicAdd(&bcnt[dst_idx[e] >> 4], 1);
    __syncthreads();
    for (int i = tid; i < NB; i += 512) {
      const int cnt = bcnt[i];
      gbase[i] = (cnt > 0) ? atomicAdd(&gcursor[i], cnt) : 0;
      bcnt[i] = 0;  // reuse as rank counter
    }
    __syncthreads();
    for (int e = e0 + tid; e < e1; e += 512) {
      const int d = dst_idx[e];
      const int s = src_idx[e];
      const int b = d >> 4;
      const int r = atomicAdd(&bcnt[b], 1);
      const int pos = gbase[b] + r;
      if (pos < CAP)
        ebuf[(size_t)b * CAP + pos] = ((unsigned int)(d & 15) << 17) | (unsigned int)s;
    }
    return;
  }

  // ---- streaming branch: sfb[row] = bf16(sf[row]/xn[row]), rows < S ----
  const int bid = blockIdx.x - KB2;  // 0..SB-1
  // 6250 chunks of 16 rows (512 thr x 8 f32 = 16 rows x 256 cols)
  for (int chunk = bid; chunk < 6250; chunk += SB) {
    const int row = chunk * 16 + (tid >> 5);   // < 100000 exactly
    const int seg = tid & 31;                  // 8-float segment
    const float4* g = (const float4*)(sf + (size_t)row * 256 + seg * 8);
    const float4 v0 = g[0];
    const float4 v1 = g[1];
    const float inv = __builtin_amdgcn_rcpf(xn[row]);
    uint4 pk;
    pk.x = f2bf2(v0.x * inv, v0.y * inv);
    pk.y = f2bf2(v0.z * inv, v0.w * inv);
    pk.z = f2bf2(v1.x * inv, v1.y * inv);
    pk.w = f2bf2(v1.z * inv, v1.w * inv);
    *(uint4*)(sfb + (size_t)row * 256 + seg * 8) = pk;
  }
}

// K3': per-bucket sort (unchanged) -> gather sfb rows (512 B, 64 lanes x
// uint2 = 4 bf16 cols/lane) -> f32 mean in registers -> K=256 MFMA vs ewT.
// 8-deep pipelined gather: next batch's LDS index reads overlap in-flight
// global gathers.
__launch_bounds__(512)
__global__ void k3_fused(const int* __restrict__ gcursor, const unsigned int* __restrict__ ebuf,
                         const unsigned short* __restrict__ sfb,
                         const unsigned short* __restrict__ ewT,
                         float* __restrict__ out) {
  __shared__ unsigned int sls[CAP];       // sorted src list (5,120 B)
  __shared__ int hist[GT], scn[GT], cur[GT];
  __shared__ unsigned int Pu[GT][132];    // 16 x 264 bf16, 528B rows (16B-aligned, stride 4 mod 32 banks)
  const int b = blockIdx.x;
  const int tid = threadIdx.x;
  const int wave = tid >> 6, lane = tid & 63;
  const int quad = lane >> 4, l15 = lane & 15;

  int n = gcursor[b];
  if (n > CAP) n = CAP;
  const unsigned int* eb = ebuf + (size_t)b * CAP;

  // Phase A: counting-sort into LDS
  if (tid < GT) hist[tid] = 0;
  __syncthreads();
  for (int i = tid; i < n; i += 512) atomicAdd(&hist[eb[i] >> 17], 1);
  __syncthreads();
  if (tid == 0) {
    int run = 0;
#pragma unroll
    for (int i = 0; i < GT; ++i) { scn[i] = run; run += hist[i]; }
  }
  __syncthreads();
  if (tid < GT) cur[tid] = scn[tid];
  __syncthreads();
  for (int i = tid; i < n; i += 512) {
    const unsigned int e = eb[i];
    const int r = atomicAdd(&cur[e >> 17], 1);
    sls[r] = e & 0x1FFFFu;
  }
  __syncthreads();

  // Phase B: wave-per-target f32 mean over sfb rows; lane owns cols 4*lane..+3
#pragma unroll
  for (int rep = 0; rep < 2; ++rep) {
    const int tl = wave * 2 + rep;
    const int beg = scn[tl];
    const int c = hist[tl];
    float t0 = 0.f, t1 = 0.f, t2 = 0.f, t3 = 0.f;
    int e = 0;
    if (c >= 8) {
      int scur[8];
#pragma unroll
      for (int j = 0; j < 8; ++j) scur[j] = (int)sls[beg + j];
      for (; e + 16 <= c; e += 8) {
        uint2 v[8];
#pragma unroll
        for (int j = 0; j < 8; ++j)
          v[j] = *(const uint2*)(sfb + (size_t)scur[j] * 256 + 4 * lane);
        int snext[8];
#pragma unroll
        for (int j = 0; j < 8; ++j)      // LDS reads overlap in-flight gathers
          snext[j] = (int)sls[beg + e + 8 + j];
#pragma unroll
        for (int j = 0; j < 8; ++j) {
          t0 += bflo(v[j].x); t1 += bfhi(v[j].x);
          t2 += bflo(v[j].y); t3 += bfhi(v[j].y);
        }
#pragma unroll
        for (int j = 0; j < 8; ++j) scur[j] = snext[j];
      }
      { // last full batch
        uint2 v[8];
#pragma unroll
        for (int j = 0; j < 8; ++j)
          v[j] = *(const uint2*)(sfb + (size_t)scur[j] * 256 + 4 * lane);
#pragma unroll
        for (int j = 0; j < 8; ++j) {
          t0 += bflo(v[j].x); t1 += bfhi(v[j].x);
          t2 += bflo(v[j].y); t3 += bfhi(v[j].y);
        }
        e += 8;
      }
    }
    for (; e < c; ++e) {
      const int s0 = (int)sls[beg + e];
      const uint2 v0 = *(const uint2*)(sfb + (size_t)s0 * 256 + 4 * lane);
      t0 += bflo(v0.x); t1 += bfhi(v0.x);
      t2 += bflo(v0.y); t3 += bfhi(v0.y);
    }
    const float inv = (c > 0) ? __builtin_amdgcn_rcpf((float)c) : 0.f;
    Pu[tl][2 * lane]     = f2bf2(t0 * inv, t1 * inv);   // cols 4*lane, 4*lane+1
    Pu[tl][2 * lane + 1] = f2bf2(t2 * inv, t3 * inv);   // cols 4*lane+2, 4*lane+3
  }
  __syncthreads();

  // Phase C: out[b*16 .. +15][:] = P(16x256) @ EW(256x128), K=256 in 8 MFMA
  const int ncol = wave * 16 + l15;
  const unsigned short* wT = ewT + (size_t)ncol * 256;
  bf16x8 wb[8];
#pragma unroll
  for (int kc = 0; kc < 8; ++kc)
    wb[kc] = *(const bf16x8*)(wT + kc * 32 + quad * 8);
  f32x4 o0 = (f32x4){0.f, 0.f, 0.f, 0.f};
#pragma unroll
  for (int kc = 0; kc < 8; ++kc) {
    bf16x8 p0 = *(const bf16x8*)((const unsigned short*)&Pu[l15][0] + kc * 32 + quad * 8);
    o0 = __builtin_amdgcn_mfma_f32_16x16x32_bf16(p0, wb[kc], o0, 0, 0, 0);
  }
#pragma unroll
  for (int reg = 0; reg < 4; ++reg)
    out[((size_t)b * GT + quad * 4 + reg) * 128 + ncol] = o0[reg];
}

extern "C" void kernel_launch(void* const* d_in, const int* in_sizes, int n_in,
                              void* d_out, int out_size, void* d_ws, size_t ws_size,
                              hipStream_t stream) {
  const float* sf      = (const float*)d_in[0];   // [N,256] f32 (only rows < S used)
  const int*   src_idx = (const int*)d_in[1];     // [E]
  const int*   dst_idx = (const int*)d_in[2];     // [E]
  /* d_in[3] range_list: unused */
  const float* xn      = (const float*)d_in[4];   // [N]
  const float* embed   = (const float*)d_in[5];   // [256,128]
  const float* weight  = (const float*)d_in[6];   // [128,128]
  float* out = (float*)d_out;                     // [T,128] f32

  // workspace layout (16B-aligned), total ~57.7 MB
  char* w = (char*)d_ws;
  unsigned short* sfb = (unsigned short*)(w);             // 100000*256*2 = 51,200,000
  int* gcursor        = (int*)(w + 51200000);             // 8,192 (1250 used)
  unsigned int* ebuf  = (unsigned int*)(w + 51208192);    // 1250*1280*4 = 6,400,000
  unsigned short* ewT = (unsigned short*)(w + 57608192);  // 128*256*2 = 65,536

  k0_prep<<<128, 256, 0, stream>>>(embed, weight, gcursor, ewT);
  k12_fused<<<KB2 + SB, 512, 0, stream>>>(sf, xn, sfb, src_idx, dst_idx, gcursor, ebuf);
  k3_fused<<<NB, 512, 0, stream>>>(gcursor, ebuf, sfb, ewT, out);
}

// Round 5
// 269.904 us; speedup vs baseline: 1.0549x; 1.0549x over previous
//
#include <hip/hip_runtime.h>
#include <cstdint>
#include <cstddef>

#define S_NUM 100000
#define T_NUM 20000
#define E_NUM 1000000

#define NB   1250     // buckets (T / GT)
#define GT   16       // targets per bucket
#define CAP  1280     // entries per bucket slot (mean 800, max ~950)
#define CH   4096     // edges per partition chunk
#define KB2  245      // k2-branch blocks (= chunks)
#define KB1  1563     // k1-branch blocks (= ceil(S/64))

typedef __bf16 bf16x8 __attribute__((ext_vector_type(8)));
typedef float f32x4 __attribute__((ext_vector_type(4)));

__device__ __forceinline__ unsigned short f2bf(float f) {
  unsigned int u = __float_as_uint(f);
  u += 0x7fffu + ((u >> 16) & 1u);   // round-to-nearest-even
  return (unsigned short)(u >> 16);
}
__device__ __forceinline__ unsigned int f2bf2(float lo, float hi) {
  return (unsigned int)f2bf(lo) | ((unsigned int)f2bf(hi) << 16);
}
__device__ __forceinline__ float bflo(unsigned int v) { return __uint_as_float(v << 16); }
__device__ __forceinline__ float bfhi(unsigned int v) { return __uint_as_float(v & 0xffff0000u); }

// k0: zero gcursor + pre-materialize bf16-transposed embed/weight
// (fragment-contiguous) so k1/k3 B-fragments are 16B vector loads.
__launch_bounds__(256)
__global__ void k0_prep(const float* __restrict__ embed, const float* __restrict__ weight,
                        int* __restrict__ gcursor, unsigned short* __restrict__ embedT,
                        unsigned short* __restrict__ weightT) {
  const int idx = blockIdx.x * 256 + threadIdx.x;   // 128 blocks x 256 = 32768
  if (idx < 2048) gcursor[idx] = 0;
  {
    const int col = idx & 127;
    const int k = idx >> 7;            // 0..255
    embedT[(size_t)col * 256 + k] = f2bf(embed[(size_t)k * 128 + col]);
  }
  if (idx < 16384) {
    const int n = idx & 127;
    const int k = idx >> 7;            // 0..127
    weightT[(size_t)n * 128 + k] = f2bf(weight[(size_t)k * 128 + n]);
  }
}

// K12: horizontally-fused kernel.
//   blocks [0, KB2):        edge partition into NB buckets (latency/atomic-bound)
//   blocks [KB2, KB2+KB1):  embed GEMM, 64-row tiles
// R17: split-K staging overlap. Stage cols 0..127 to LDS; ISSUE cols 128..255
// global loads into registers; raw s_barrier with only lgkmcnt(0) (NOT
// __syncthreads -- that drains vmcnt(0) and would serialize the in-flight
// loads); run kc=0..3 MFMA under the flying loads; pack+store half 2;
// barrier; kc=4..7. MFMA order unchanged (kc ascending) -> bit-identical.
__global__ void k12_fused(const float* __restrict__ sf, const float* __restrict__ xn,
                          const unsigned short* __restrict__ embedT, unsigned short* __restrict__ xb,
                          const int* __restrict__ src_idx, const int* __restrict__ dst_idx,
                          int* __restrict__ gcursor, unsigned int* __restrict__ ebuf) {
  __shared__ __align__(16) unsigned char smem[64 * 296 * 2];  // 37,888 B
  const int tid = threadIdx.x;

  if (blockIdx.x < KB2) {
    // ---- k2 branch: partition one CH-edge chunk into NB buckets ----
    int* bcnt  = (int*)smem;                 // NB ints
    int* gbase = (int*)(smem + 5120);        // NB ints
    const int e0 = blockIdx.x * CH;
    const int e1 = (e0 + CH < E_NUM) ? (e0 + CH) : E_NUM;
    for (int i = tid; i < NB; i += 512) bcnt[i] = 0;
    __syncthreads();
    for (int e = e0 + tid; e < e1; e += 512)
      atomicAdd(&bcnt[dst_idx[e] >> 4], 1);
    __syncthreads();
    for (int i = tid; i < NB; i += 512) {
      const int cnt = bcnt[i];
      gbase[i] = (cnt > 0) ? atomicAdd(&gcursor[i], cnt) : 0;
      bcnt[i] = 0;  // reuse as rank counter
    }
    __syncthreads();
    for (int e = e0 + tid; e < e1; e += 512) {
      const int d = dst_idx[e];
      const int s = src_idx[e];
      const int b = d >> 4;
      const int r = atomicAdd(&bcnt[b], 1);
      const int pos = gbase[b] + r;
      if (pos < CAP)
        ebuf[(size_t)b * CAP + pos] = ((unsigned int)(d & 15) << 17) | (unsigned int)s;
    }
    return;
  }

  // ---- k1 branch: xb[64-row tile] = bf16((sf @ embed) / xn) ----
  unsigned short (*lA)[296] = (unsigned short (*)[296])smem;
  unsigned short (*lC)[136] = (unsigned short (*)[136])smem;
  const int wave = tid >> 6;      // 0..7, each wave owns 16 output cols
  const int lane = tid & 63;
  const int quad = lane >> 4;
  const int l15 = lane & 15;
  const int row0 = (blockIdx.x - KB2) * 64;
  const int col0 = wave * 16;
  const unsigned short* ebT = embedT + (size_t)(col0 + l15) * 256;

  // pass A: stage cols 0..127 (f32 -> bf16), 2 x (512 thr x 16 rows-slice)
#pragma unroll
  for (int i = 0; i < 2; ++i) {
    const int idx = i * 512 + tid;        // 0..1023
    const int row = idx >> 4;             // 0..63
    const int sg  = idx & 15;             // 8-float segment in [0,16)
    // rows row0+row <= 100031 < N=120000: in-bounds (junk rows dropped at store)
    const float4* g = (const float4*)(sf + (size_t)(row0 + row) * 256 + sg * 8);
    const float4 v0 = g[0];
    const float4 v1 = g[1];
    uint4 pk;
    pk.x = f2bf2(v0.x, v0.y);
    pk.y = f2bf2(v0.z, v0.w);
    pk.z = f2bf2(v1.x, v1.y);
    pk.w = f2bf2(v1.z, v1.w);
    *(uint4*)&lA[row][sg * 8] = pk;
  }
  // pass B: issue cols 128..255 loads NOW (consumed after first MFMA half)
  float4 b00, b01, b10, b11;
  {
    const int r0 = tid >> 4, s0 = tid & 15;
    const float4* g0 = (const float4*)(sf + (size_t)(row0 + r0) * 256 + 128 + s0 * 8);
    b00 = g0[0]; b01 = g0[1];
    const int idx1 = 512 + tid;
    const int r1 = idx1 >> 4, s1 = idx1 & 15;
    const float4* g1 = (const float4*)(sf + (size_t)(row0 + r1) * 256 + 128 + s1 * 8);
    b10 = g1[0]; b11 = g1[1];
  }
  bf16x8 fbn = *(const bf16x8*)(ebT + quad * 8);   // kc=0 prefetch (1-deep pipe)

  // raw barrier: drain only LDS writes; keep pass-B vmem loads in flight
  asm volatile("s_waitcnt lgkmcnt(0)" ::: "memory");
  __builtin_amdgcn_s_barrier();

  f32x4 acc[4];
#pragma unroll
  for (int i = 0; i < 4; ++i) acc[i] = (f32x4){0.f, 0.f, 0.f, 0.f};

#pragma unroll
  for (int kc = 0; kc < 4; ++kc) {        // first K half under flying loads
    const bf16x8 fbc = fbn;
    fbn = *(const bf16x8*)(ebT + (kc + 1) * 32 + quad * 8);
#pragma unroll
    for (int rt = 0; rt < 4; ++rt) {
      bf16x8 fa = *(const bf16x8*)&lA[rt * 16 + l15][kc * 32 + quad * 8];
      acc[rt] = __builtin_amdgcn_mfma_f32_16x16x32_bf16(fa, fbc, acc[rt], 0, 0, 0);
    }
  }

  // pack & store pass B (cols 128..255; disjoint from cols 0..127 being read)
  {
    const int r0 = tid >> 4, s0 = tid & 15;
    uint4 pk;
    pk.x = f2bf2(b00.x, b00.y);
    pk.y = f2bf2(b00.z, b00.w);
    pk.z = f2bf2(b01.x, b01.y);
    pk.w = f2bf2(b01.z, b01.w);
    *(uint4*)&lA[r0][128 + s0 * 8] = pk;
    const int idx1 = 512 + tid;
    const int r1 = idx1 >> 4, s1 = idx1 & 15;
    pk.x = f2bf2(b10.x, b10.y);
    pk.y = f2bf2(b10.z, b10.w);
    pk.z = f2bf2(b11.x, b11.y);
    pk.w = f2bf2(b11.z, b11.w);
    *(uint4*)&lA[r1][128 + s1 * 8] = pk;
  }
  asm volatile("s_waitcnt lgkmcnt(0)" ::: "memory");
  __builtin_amdgcn_s_barrier();

#pragma unroll
  for (int kc = 4; kc < 8; ++kc) {        // second K half
    const bf16x8 fbc = fbn;
    if (kc < 7) fbn = *(const bf16x8*)(ebT + (kc + 1) * 32 + quad * 8);
#pragma unroll
    for (int rt = 0; rt < 4; ++rt) {
      bf16x8 fa = *(const bf16x8*)&lA[rt * 16 + l15][kc * 32 + quad * 8];
      acc[rt] = __builtin_amdgcn_mfma_f32_16x16x32_bf16(fa, fbc, acc[rt], 0, 0, 0);
    }
  }
  __syncthreads();  // done reading lA; smem becomes lC

  // acc -> LDS (row = rt*16+quad*4+reg, col = col0+l15), scaled by 1/xn
#pragma unroll
  for (int rt = 0; rt < 4; ++rt) {
#pragma unroll
    for (int reg = 0; reg < 4; ++reg) {
      const int row = rt * 16 + quad * 4 + reg;
      const float inv = __builtin_amdgcn_rcpf(xn[row0 + row]);
      lC[row][col0 + l15] = f2bf(acc[rt][reg] * inv);
    }
  }
  __syncthreads();

  // coalesced out: 2 passes x 512 thr x 16B = full 256B rows
#pragma unroll
  for (int p = 0; p < 2; ++p) {
    const int i = p * 512 + tid;
    const int row = i >> 4;
    const int seg = i & 15;
    const int gr = row0 + row;
    if (gr < S_NUM)
      *(uint4*)(xb + (size_t)gr * 128 + seg * 8) = *(const uint4*)&lC[row][seg * 8];
  }
}

// K3 (fused sort + aggregate + output GEMM). One block (512 thr, 8 waves)
// per 16-target bucket; 1250 blocks.
// R17: Phase B double-buffers the gather (vA/vB, fixed names -- no runtime
// indexing) so 16 row-loads stay in flight per wave instead of 8. Batches
// are consumed strictly in order -> bit-identical accumulation.
__launch_bounds__(512)
__global__ void k3_fused(const int* __restrict__ gcursor, const unsigned int* __restrict__ ebuf,
                         const unsigned short* __restrict__ xb,
                         const unsigned short* __restrict__ weightT,
                         float* __restrict__ out) {
  __shared__ unsigned int sls[CAP];       // sorted src list (5,120 B)
  __shared__ int hist[GT], scn[GT], cur[GT];
  __shared__ unsigned int Pu[GT][68];     // packed bf16 pairs, padded (4,352 B)
  const int b = blockIdx.x;
  const int tid = threadIdx.x;
  const int wave = tid >> 6, lane = tid & 63;
  const int quad = lane >> 4, l15 = lane & 15;

  int n = gcursor[b];
  if (n > CAP) n = CAP;
  const unsigned int* eb = ebuf + (size_t)b * CAP;

  // Phase A: counting-sort into LDS
  if (tid < GT) hist[tid] = 0;
  __syncthreads();
  for (int i = tid; i < n; i += 512) atomicAdd(&hist[eb[i] >> 17], 1);
  __syncthreads();
  if (tid == 0) {
    int run = 0;
#pragma unroll
    for (int i = 0; i < GT; ++i) { scn[i] = run; run += hist[i]; }
  }
  __syncthreads();
  if (tid < GT) cur[tid] = scn[tid];
  __syncthreads();
  for (int i = tid; i < n; i += 512) {
    const unsigned int e = eb[i];
    const int r = atomicAdd(&cur[e >> 17], 1);
    sls[r] = e & 0x1FFFFu;
  }
  __syncthreads();

  // Phase B: wave-per-target mean aggregation; 2 edges per load via h-split,
  // two 8-load batches (16 rows) in flight per wave.
  const int h = lane >> 5;          // 0: even local edges, 1: odd
  const int cq = lane & 31;         // col group: cols 4cq..4cq+3
#pragma unroll
  for (int rep = 0; rep < 2; ++rep) {
    const int tl = wave * 2 + rep;
    const int beg = scn[tl];
    const int c = hist[tl];
    float t0 = 0.f, t1 = 0.f, t2 = 0.f, t3 = 0.f;
    int e = 0;
    const int nb = c >> 4;          // full 16-edge batches
    if (nb >= 2) {
      int sA[8], sB[8];
      uint2 vA[8], vB[8];
#pragma unroll
      for (int j = 0; j < 8; ++j) sA[j] = (int)sls[beg + 2 * j + h];
#pragma unroll
      for (int j = 0; j < 8; ++j) vA[j] = *(const uint2*)(xb + (size_t)sA[j] * 128 + 4 * cq);
#pragma unroll
      for (int j = 0; j < 8; ++j) sB[j] = (int)sls[beg + 16 + 2 * j + h];
#pragma unroll
      for (int j = 0; j < 8; ++j) vB[j] = *(const uint2*)(xb + (size_t)sB[j] * 128 + 4 * cq);
      int bi = 0;
      for (; bi + 3 < nb; bi += 2) {
#pragma unroll
        for (int j = 0; j < 8; ++j) {                      // consume batch bi
          t0 += bflo(vA[j].x); t1 += bfhi(vA[j].x);
          t2 += bflo(vA[j].y); t3 += bfhi(vA[j].y);
        }
#pragma unroll
        for (int j = 0; j < 8; ++j) sA[j] = (int)sls[beg + (bi + 2) * 16 + 2 * j + h];
#pragma unroll
        for (int j = 0; j < 8; ++j) vA[j] = *(const uint2*)(xb + (size_t)sA[j] * 128 + 4 * cq);
#pragma unroll
        for (int j = 0; j < 8; ++j) {                      // consume batch bi+1
          t0 += bflo(vB[j].x); t1 += bfhi(vB[j].x);
          t2 += bflo(vB[j].y); t3 += bfhi(vB[j].y);
        }
#pragma unroll
        for (int j = 0; j < 8; ++j) sB[j] = (int)sls[beg + (bi + 3) * 16 + 2 * j + h];
#pragma unroll
        for (int j = 0; j < 8; ++j) vB[j] = *(const uint2*)(xb + (size_t)sB[j] * 128 + 4 * cq);
      }
      if (nb - bi == 3) {
#pragma unroll
        for (int j = 0; j < 8; ++j) {                      // consume batch bi
          t0 += bflo(vA[j].x); t1 += bfhi(vA[j].x);
          t2 += bflo(vA[j].y); t3 += bfhi(vA[j].y);
        }
#pragma unroll
        for (int j = 0; j < 8; ++j) sA[j] = (int)sls[beg + (bi + 2) * 16 + 2 * j + h];
#pragma unroll
        for (int j = 0; j < 8; ++j) vA[j] = *(const uint2*)(xb + (size_t)sA[j] * 128 + 4 * cq);
#pragma unroll
        for (int j = 0; j < 8; ++j) {                      // consume batch bi+1
          t0 += bflo(vB[j].x); t1 += bfhi(vB[j].x);
          t2 += bflo(vB[j].y); t3 += bfhi(vB[j].y);
        }
#pragma unroll
        for (int j = 0; j < 8; ++j) {                      // consume batch bi+2
          t0 += bflo(vA[j].x); t1 += bfhi(vA[j].x);
          t2 += bflo(vA[j].y); t3 += bfhi(vA[j].y);
        }
      } else {  // nb - bi == 2
#pragma unroll
        for (int j = 0; j < 8; ++j) {
          t0 += bflo(vA[j].x); t1 += bfhi(vA[j].x);
          t2 += bflo(vA[j].y); t3 += bfhi(vA[j].y);
        }
#pragma unroll
        for (int j = 0; j < 8; ++j) {
          t0 += bflo(vB[j].x); t1 += bfhi(vB[j].x);
          t2 += bflo(vB[j].y); t3 += bfhi(vB[j].y);
        }
      }
      e = nb * 16;
    } else if (nb == 1) {
      int s[8];
#pragma unroll
      for (int j = 0; j < 8; ++j) s[j] = (int)sls[beg + 2 * j + h];
      uint2 v[8];
#pragma unroll
      for (int j = 0; j < 8; ++j) v[j] = *(const uint2*)(xb + (size_t)s[j] * 128 + 4 * cq);
#pragma unroll
      for (int j = 0; j < 8; ++j) {
        t0 += bflo(v[j].x); t1 += bfhi(v[j].x);
        t2 += bflo(v[j].y); t3 += bfhi(v[j].y);
      }
      e = 16;
    }
    for (; e + 2 <= c; e += 2) {
      const int s0 = (int)sls[beg + e + h];
      const uint2 v0 = *(const uint2*)(xb + (size_t)s0 * 128 + 4 * cq);
      t0 += bflo(v0.x); t1 += bfhi(v0.x);
      t2 += bflo(v0.y); t3 += bfhi(v0.y);
    }
    if ((c & 1) && h == 0) {        // last odd edge belongs to the even group
      const int s0 = (int)sls[beg + c - 1];
      const uint2 v0 = *(const uint2*)(xb + (size_t)s0 * 128 + 4 * cq);
      t0 += bflo(v0.x); t1 += bfhi(v0.x);
      t2 += bflo(v0.y); t3 += bfhi(v0.y);
    }
    // combine even-group + odd-group (single cross-add, same as champion)
    t0 += __shfl_xor(t0, 32, 64);
    t1 += __shfl_xor(t1, 32, 64);
    t2 += __shfl_xor(t2, 32, 64);
    t3 += __shfl_xor(t3, 32, 64);
    const float inv = (c > 0) ? __builtin_amdgcn_rcpf((float)c) : 0.f;
    const unsigned int pk = h ? f2bf2(t2 * inv, t3 * inv) : f2bf2(t0 * inv, t1 * inv);
    Pu[tl][2 * cq + h] = pk;        // lane h=0 -> cols 4cq..+1, h=1 -> cols 4cq+2..+3
  }
  __syncthreads();

  // Phase C: out[b*16 .. b*16+15][:] = P @ W via one MFMA m-tile per wave-col
  const int ncol = wave * 16 + l15;
  const unsigned short* wT = weightT + (size_t)ncol * 128;
  bf16x8 wb[4];
#pragma unroll
  for (int kc = 0; kc < 4; ++kc)
    wb[kc] = *(const bf16x8*)(wT + kc * 32 + quad * 8);
  f32x4 o0 = (f32x4){0.f, 0.f, 0.f, 0.f};
#pragma unroll
  for (int kc = 0; kc < 4; ++kc) {
    bf16x8 p0 = *(const bf16x8*)((const unsigned short*)&Pu[l15][0] + kc * 32 + quad * 8);
    o0 = __builtin_amdgcn_mfma_f32_16x16x32_bf16(p0, wb[kc], o0, 0, 0, 0);
  }
#pragma unroll
  for (int reg = 0; reg < 4; ++reg)
    out[((size_t)b * GT + quad * 4 + reg) * 128 + ncol] = o0[reg];
}

extern "C" void kernel_launch(void* const* d_in, const int* in_sizes, int n_in,
                              void* d_out, int out_size, void* d_ws, size_t ws_size,
                              hipStream_t stream) {
  const float* sf      = (const float*)d_in[0];   // [N,256] f32 (only rows < S used)
  const int*   src_idx = (const int*)d_in[1];     // [E]
  const int*   dst_idx = (const int*)d_in[2];     // [E]
  /* d_in[3] range_list: unused */
  const float* xn      = (const float*)d_in[4];   // [N]
  const float* embed   = (const float*)d_in[5];   // [256,128]
  const float* weight  = (const float*)d_in[6];   // [128,128]
  float* out = (float*)d_out;                     // [T,128] f32

  // workspace layout (16B-aligned), total ~32.1 MB
  char* w = (char*)d_ws;
  unsigned short* xb      = (unsigned short*)(w);                // 25,600,000
  int* gcursor            = (int*)(w + 25600000);                // 8,192 (1250 used)
  unsigned int* ebuf      = (unsigned int*)(w + 25608192);       // 1250*1280*4 = 6,400,000
  unsigned short* embedT  = (unsigned short*)(w + 32008192);     // 128*256*2 = 65,536
  unsigned short* weightT = (unsigned short*)(w + 32073728);     // 128*128*2 = 32,768

  k0_prep<<<128, 256, 0, stream>>>(embed, weight, gcursor, embedT, weightT);
  k12_fused<<<KB2 + KB1, 512, 0, stream>>>(sf, xn, embedT, xb, src_idx, dst_idx, gcursor, ebuf);
  k3_fused<<<NB, 512, 0, stream>>>(gcursor, ebuf, xb, weightT, out);
}

// Round 6
// 255.682 us; speedup vs baseline: 1.1136x; 1.0556x over previous
//
#include <hip/hip_runtime.h>
#include <cstdint>
#include <cstddef>

#define S_NUM 100000
#define T_NUM 20000
#define E_NUM 1000000

#define NB   1250     // buckets (T / GT)
#define GT   16       // targets per bucket
#define CAP  1280     // entries per bucket slot (mean 800, max ~950)
#define CH   4096     // edges per partition chunk
#define KB2  245      // partition blocks (= chunks), scheduled LAST
#define KB1  1563     // GEMM tile blocks (= ceil(S/64)), scheduled FIRST

typedef __bf16 bf16x8 __attribute__((ext_vector_type(8)));
typedef float f32x4 __attribute__((ext_vector_type(4)));
typedef unsigned int u32_g __attribute__((address_space(1)));
typedef unsigned int u32_l __attribute__((address_space(3)));

__device__ __forceinline__ unsigned short f2bf(float f) {
  unsigned int u = __float_as_uint(f);
  u += 0x7fffu + ((u >> 16) & 1u);   // round-to-nearest-even
  return (unsigned short)(u >> 16);
}
__device__ __forceinline__ unsigned int f2bf2(float lo, float hi) {
  return (unsigned int)f2bf(lo) | ((unsigned int)f2bf(hi) << 16);
}
__device__ __forceinline__ float bflo(unsigned int v) { return __uint_as_float(v << 16); }
__device__ __forceinline__ float bfhi(unsigned int v) { return __uint_as_float(v & 0xffff0000u); }

// k0: zero gcursor + pre-materialize bf16-transposed embed/weight
// (fragment-contiguous) so k1/k3 B-fragments are 16B vector loads.
__launch_bounds__(256)
__global__ void k0_prep(const float* __restrict__ embed, const float* __restrict__ weight,
                        int* __restrict__ gcursor, unsigned short* __restrict__ embedT,
                        unsigned short* __restrict__ weightT) {
  const int idx = blockIdx.x * 256 + threadIdx.x;   // 128 blocks x 256 = 32768
  if (idx < 2048) gcursor[idx] = 0;
  {
    const int col = idx & 127;
    const int k = idx >> 7;            // 0..255
    embedT[(size_t)col * 256 + k] = f2bf(embed[(size_t)k * 128 + col]);
  }
  if (idx < 16384) {
    const int n = idx & 127;
    const int k = idx >> 7;            // 0..127
    weightT[(size_t)n * 128 + k] = f2bf(weight[(size_t)k * 128 + n]);
  }
}

// K12 R18: GEMM branch staged via global_load_lds (async DMA, no VGPR
// round-trip). R17's PMC showed the staging was latency-bound with only
// ~2 loads in flight (VGPR=32, HBM 19.6%, all pipes idle). Here the whole
// 64 KB f32 tile is in flight at once: 8 x global_load_lds_dwordx4 per
// thread, LDS-linear dest (wave-uniform base + lane*16), contiguous global
// src (tile rows are contiguous in sf). Then an in-LDS convert pass
// (read-own f32 -> regs -> barrier -> f2bf2 -> stride-296 bf16 tile aliased
// over the f32 buffer) feeds the champion MFMA path unchanged ->
// bit-identical output. GEMM blocks first; partition blocks fill the tail.
__launch_bounds__(512, 4)
__global__ void k12_fused(const float* __restrict__ sf, const float* __restrict__ xn,
                          const unsigned short* __restrict__ embedT, unsigned short* __restrict__ xb,
                          const int* __restrict__ src_idx, const int* __restrict__ dst_idx,
                          int* __restrict__ gcursor, unsigned int* __restrict__ ebuf) {
  __shared__ __align__(16) unsigned char smem[65536];  // 64 KB: f32 tile, then aliased lA/lC
  const int tid = threadIdx.x;

  if (blockIdx.x >= KB1) {
    // ---- partition branch: one CH-edge chunk into NB buckets ----
    int* bcnt  = (int*)smem;                 // NB ints
    int* gbase = (int*)(smem + 5120);        // NB ints
    const int e0 = (blockIdx.x - KB1) * CH;
    const int e1 = (e0 + CH < E_NUM) ? (e0 + CH) : E_NUM;
    for (int i = tid; i < NB; i += 512) bcnt[i] = 0;
    __syncthreads();
    for (int e = e0 + tid; e < e1; e += 512)
      atomicAdd(&bcnt[dst_idx[e] >> 4], 1);
    __syncthreads();
    for (int i = tid; i < NB; i += 512) {
      const int cnt = bcnt[i];
      gbase[i] = (cnt > 0) ? atomicAdd(&gcursor[i], cnt) : 0;
      bcnt[i] = 0;  // reuse as rank counter
    }
    __syncthreads();
    for (int e = e0 + tid; e < e1; e += 512) {
      const int d = dst_idx[e];
      const int s = src_idx[e];
      const int b = d >> 4;
      const int r = atomicAdd(&bcnt[b], 1);
      const int pos = gbase[b] + r;
      if (pos < CAP)
        ebuf[(size_t)b * CAP + pos] = ((unsigned int)(d & 15) << 17) | (unsigned int)s;
    }
    return;
  }

  // ---- GEMM branch: xb[64-row tile] = bf16((sf @ embed) / xn) ----
  const int wave = tid >> 6;      // 0..7, each wave owns 16 output cols
  const int lane = tid & 63;
  const int quad = lane >> 4;
  const int l15 = lane & 15;
  const int row0 = blockIdx.x * 64;
  const int col0 = wave * 16;
  const unsigned short* ebT = embedT + (size_t)(col0 + l15) * 256;

  // 1. async-stage 64 KB f32 tile -> LDS (linear; rows contiguous in sf).
  //    rows row0..row0+63 <= 100031 < N=120000: in-bounds (junk rows dropped at store)
  {
    const char* gsrc = (const char*)(sf + (size_t)row0 * 256);
#pragma unroll
    for (int j = 0; j < 8; ++j) {
      const char* gp = gsrc + (size_t)(j * 512 + tid) * 16;       // per-lane global src
      unsigned char* lp = smem + (size_t)(j * 512 + wave * 64) * 16;  // wave-uniform dest
      __builtin_amdgcn_global_load_lds((const u32_g*)gp, (u32_l*)lp, 16, 0, 0);
    }
  }
  // 2. B fragments (L2-hot) load while the DMA is in flight
  bf16x8 fb[8];
#pragma unroll
  for (int kc = 0; kc < 8; ++kc)
    fb[kc] = *(const bf16x8*)(ebT + kc * 32 + quad * 8);
  __syncthreads();   // drains vmcnt: tile + fb resident

  // 3. convert pass: each thread owns 8 float4 slots (slot = tid + k*512
  //    -> row = (tid>>6) + 8k = wave+8k, cols 4*lane..+3), reads all to
  //    regs, barrier, writes bf16 into stride-296 lA aliased over smem.
  f32x4 vf[8];
#pragma unroll
  for (int k = 0; k < 8; ++k)
    vf[k] = *(const f32x4*)(smem + (size_t)tid * 16 + (size_t)k * 8192);
  __syncthreads();   // all f32 reads complete; safe to overwrite with lA
  unsigned short (*lA)[296] = (unsigned short (*)[296])smem;
  unsigned short (*lC)[136] = (unsigned short (*)[136])smem;
#pragma unroll
  for (int k = 0; k < 8; ++k) {
    const int r = wave + 8 * k;
    const int c = lane * 4;
    uint2 pk;
    pk.x = f2bf2(vf[k][0], vf[k][1]);
    pk.y = f2bf2(vf[k][2], vf[k][3]);
    *(uint2*)&lA[r][c] = pk;       // per-wave: consecutive 8B, conflict-free
  }
  __syncthreads();

  // 4. MFMA inner loop (champion path, 0-conflict stride-296 fragment reads)
  f32x4 acc[4];
#pragma unroll
  for (int i = 0; i < 4; ++i) acc[i] = (f32x4){0.f, 0.f, 0.f, 0.f};
#pragma unroll
  for (int kc = 0; kc < 8; ++kc)
#pragma unroll
    for (int rt = 0; rt < 4; ++rt) {
      bf16x8 fa = *(const bf16x8*)&lA[rt * 16 + l15][kc * 32 + quad * 8];
      acc[rt] = __builtin_amdgcn_mfma_f32_16x16x32_bf16(fa, fb[kc], acc[rt], 0, 0, 0);
    }
  __syncthreads();  // done reading lA; smem becomes lC

  // acc -> LDS (row = rt*16+quad*4+reg, col = col0+l15), scaled by 1/xn
#pragma unroll
  for (int rt = 0; rt < 4; ++rt) {
#pragma unroll
    for (int reg = 0; reg < 4; ++reg) {
      const int row = rt * 16 + quad * 4 + reg;
      const float inv = __builtin_amdgcn_rcpf(xn[row0 + row]);
      lC[row][col0 + l15] = f2bf(acc[rt][reg] * inv);
    }
  }
  __syncthreads();

  // coalesced out: 2 passes x 512 thr x 16B = full 256B rows
#pragma unroll
  for (int p = 0; p < 2; ++p) {
    const int i = p * 512 + tid;
    const int row = i >> 4;
    const int seg = i & 15;
    const int gr = row0 + row;
    if (gr < S_NUM)
      *(uint4*)(xb + (size_t)gr * 128 + seg * 8) = *(const uint4*)&lC[row][seg * 8];
  }
}

// K3 (fused sort + aggregate + output GEMM) — exact R13 champion version.
__launch_bounds__(512)
__global__ void k3_fused(const int* __restrict__ gcursor, const unsigned int* __restrict__ ebuf,
                         const unsigned short* __restrict__ xb,
                         const unsigned short* __restrict__ weightT,
                         float* __restrict__ out) {
  __shared__ unsigned int sls[CAP];       // sorted src list (5,120 B)
  __shared__ int hist[GT], scn[GT], cur[GT];
  __shared__ unsigned int Pu[GT][68];     // packed bf16 pairs, padded (4,352 B)
  const int b = blockIdx.x;
  const int tid = threadIdx.x;
  const int wave = tid >> 6, lane = tid & 63;
  const int quad = lane >> 4, l15 = lane & 15;

  int n = gcursor[b];
  if (n > CAP) n = CAP;
  const unsigned int* eb = ebuf + (size_t)b * CAP;

  // Phase A: counting-sort into LDS
  if (tid < GT) hist[tid] = 0;
  __syncthreads();
  for (int i = tid; i < n; i += 512) atomicAdd(&hist[eb[i] >> 17], 1);
  __syncthreads();
  if (tid == 0) {
    int run = 0;
#pragma unroll
    for (int i = 0; i < GT; ++i) { scn[i] = run; run += hist[i]; }
  }
  __syncthreads();
  if (tid < GT) cur[tid] = scn[tid];
  __syncthreads();
  for (int i = tid; i < n; i += 512) {
    const unsigned int e = eb[i];
    const int r = atomicAdd(&cur[e >> 17], 1);
    sls[r] = e & 0x1FFFFu;
  }
  __syncthreads();

  // Phase B: wave-per-target mean aggregation, paired-edge gather
  const int h = lane >> 5;          // 0: even local edges, 1: odd
  const int cq = lane & 31;         // col group: cols 4cq..4cq+3
#pragma unroll
  for (int rep = 0; rep < 2; ++rep) {
    const int tl = wave * 2 + rep;
    const int beg = scn[tl];
    const int c = hist[tl];
    float t0 = 0.f, t1 = 0.f, t2 = 0.f, t3 = 0.f;
    int e = 0;
    for (; e + 16 <= c; e += 16) {
      int s[8];
#pragma unroll
      for (int j = 0; j < 8; ++j) s[j] = (int)sls[beg + e + 2 * j + h];  // 2-addr LDS read
      uint2 v[8];
#pragma unroll
      for (int j = 0; j < 8; ++j)
        v[j] = *(const uint2*)(xb + (size_t)s[j] * 128 + 4 * cq);
#pragma unroll
      for (int j = 0; j < 8; ++j) {
        t0 += bflo(v[j].x); t1 += bfhi(v[j].x);
        t2 += bflo(v[j].y); t3 += bfhi(v[j].y);
      }
    }
    for (; e + 2 <= c; e += 2) {
      const int s0 = (int)sls[beg + e + h];
      const uint2 v0 = *(const uint2*)(xb + (size_t)s0 * 128 + 4 * cq);
      t0 += bflo(v0.x); t1 += bfhi(v0.x);
      t2 += bflo(v0.y); t3 += bfhi(v0.y);
    }
    if ((c & 1) && h == 0) {        // last odd edge belongs to the even group
      const int s0 = (int)sls[beg + c - 1];
      const uint2 v0 = *(const uint2*)(xb + (size_t)s0 * 128 + 4 * cq);
      t0 += bflo(v0.x); t1 += bfhi(v0.x);
      t2 += bflo(v0.y); t3 += bfhi(v0.y);
    }
    // combine even-group + odd-group (single cross-add, same as old a+b)
    t0 += __shfl_xor(t0, 32, 64);
    t1 += __shfl_xor(t1, 32, 64);
    t2 += __shfl_xor(t2, 32, 64);
    t3 += __shfl_xor(t3, 32, 64);
    const float inv = (c > 0) ? __builtin_amdgcn_rcpf((float)c) : 0.f;
    const unsigned int pk = h ? f2bf2(t2 * inv, t3 * inv) : f2bf2(t0 * inv, t1 * inv);
    Pu[tl][2 * cq + h] = pk;        // lane h=0 -> cols 4cq..+1, h=1 -> cols 4cq+2..+3
  }
  __syncthreads();

  // Phase C: out[b*16 .. b*16+15][:] = P @ W via one MFMA m-tile per wave-col
  const int ncol = wave * 16 + l15;
  const unsigned short* wT = weightT + (size_t)ncol * 128;
  bf16x8 wb[4];
#pragma unroll
  for (int kc = 0; kc < 4; ++kc)
    wb[kc] = *(const bf16x8*)(wT + kc * 32 + quad * 8);
  f32x4 o0 = (f32x4){0.f, 0.f, 0.f, 0.f};
#pragma unroll
  for (int kc = 0; kc < 4; ++kc) {
    bf16x8 p0 = *(const bf16x8*)((const unsigned short*)&Pu[l15][0] + kc * 32 + quad * 8);
    o0 = __builtin_amdgcn_mfma_f32_16x16x32_bf16(p0, wb[kc], o0, 0, 0, 0);
  }
#pragma unroll
  for (int reg = 0; reg < 4; ++reg)
    out[((size_t)b * GT + quad * 4 + reg) * 128 + ncol] = o0[reg];
}

extern "C" void kernel_launch(void* const* d_in, const int* in_sizes, int n_in,
                              void* d_out, int out_size, void* d_ws, size_t ws_size,
                              hipStream_t stream) {
  const float* sf      = (const float*)d_in[0];   // [N,256] f32 (only rows < S used)
  const int*   src_idx = (const int*)d_in[1];     // [E]
  const int*   dst_idx = (const int*)d_in[2];     // [E]
  /* d_in[3] range_list: unused */
  const float* xn      = (const float*)d_in[4];   // [N]
  const float* embed   = (const float*)d_in[5];   // [256,128]
  const float* weight  = (const float*)d_in[6];   // [128,128]
  float* out = (float*)d_out;                     // [T,128] f32

  // workspace layout (16B-aligned), total ~32.1 MB
  char* w = (char*)d_ws;
  unsigned short* xb      = (unsigned short*)(w);                // 25,600,000
  int* gcursor            = (int*)(w + 25600000);                // 8,192 (1250 used)
  unsigned int* ebuf      = (unsigned int*)(w + 25608192);       // 1250*1280*4 = 6,400,000
  unsigned short* embedT  = (unsigned short*)(w + 32008192);     // 128*256*2 = 65,536
  unsigned short* weightT = (unsigned short*)(w + 32073728);     // 128*128*2 = 32,768

  k0_prep<<<128, 256, 0, stream>>>(embed, weight, gcursor, embedT, weightT);
  k12_fused<<<KB1 + KB2, 512, 0, stream>>>(sf, xn, embedT, xb, src_idx, dst_idx, gcursor, ebuf);
  k3_fused<<<NB, 512, 0, stream>>>(gcursor, ebuf, xb, weightT, out);
}

// Round 7
// 253.823 us; speedup vs baseline: 1.1218x; 1.0073x over previous
//
#include <hip/hip_runtime.h>
#include <cstdint>
#include <cstddef>

#define S_NUM 100000
#define T_NUM 20000
#define E_NUM 1000000

#define NB   1250     // buckets (T / GT)
#define GT   16       // targets per bucket
#define CAP  1280     // entries per bucket slot (mean 800, max ~950)
#define CH   4096     // edges per partition chunk
#define KB2  245      // partition blocks (= chunks), tail of the grid
#define KB1  1563     // GEMM tiles (= ceil(S/64))
#define KBG  782      // GEMM blocks; each handles tiles {bid, bid+KBG}

typedef __bf16 bf16x8 __attribute__((ext_vector_type(8)));
typedef float f32x4 __attribute__((ext_vector_type(4)));

__device__ __forceinline__ unsigned short f2bf(float f) {
  unsigned int u = __float_as_uint(f);
  u += 0x7fffu + ((u >> 16) & 1u);   // round-to-nearest-even
  return (unsigned short)(u >> 16);
}
__device__ __forceinline__ unsigned int f2bf2(float lo, float hi) {
  return (unsigned int)f2bf(lo) | ((unsigned int)f2bf(hi) << 16);
}
__device__ __forceinline__ float bflo(unsigned int v) { return __uint_as_float(v << 16); }
__device__ __forceinline__ float bfhi(unsigned int v) { return __uint_as_float(v & 0xffff0000u); }

// k0: zero gcursor + pre-materialize bf16-transposed embed/weight
// (fragment-contiguous) so k1/k3 B-fragments are 16B vector loads.
__launch_bounds__(256)
__global__ void k0_prep(const float* __restrict__ embed, const float* __restrict__ weight,
                        int* __restrict__ gcursor, unsigned short* __restrict__ embedT,
                        unsigned short* __restrict__ weightT) {
  const int idx = blockIdx.x * 256 + threadIdx.x;   // 128 blocks x 256 = 32768
  if (idx < 2048) gcursor[idx] = 0;
  {
    const int col = idx & 127;
    const int k = idx >> 7;            // 0..255
    embedT[(size_t)col * 256 + k] = f2bf(embed[(size_t)k * 128 + col]);
  }
  if (idx < 16384) {
    const int n = idx & 127;
    const int k = idx >> 7;            // 0..127
    weightT[(size_t)n * 128 + k] = f2bf(weight[(size_t)k * 128 + n]);
  }
}

// K12 R19: workgroup-count test. Evidence (R13..R18): duration invariant to
// occupancy, ILP, DMA strategy, round count; visible dispatches all cluster
// at ~20-27 workgroups/us. Hypothesis: per-WG dispatch overhead dominates.
// Grid cut 1808 -> 1027: blocks [0,KBG) each run TWO 64-row GEMM tiles
// (t = bid, bid+KBG) with the champion body bit-identical per tile; blocks
// [KBG, KBG+KB2) run the partition chunks. fb fragments loaded once per
// block (tile-invariant). 37.9 KB LDS -> 4 blocks/CU -> all 1027 resident.
__launch_bounds__(512)
__global__ void k12_fused(const float* __restrict__ sf, const float* __restrict__ xn,
                          const unsigned short* __restrict__ embedT, unsigned short* __restrict__ xb,
                          const int* __restrict__ src_idx, const int* __restrict__ dst_idx,
                          int* __restrict__ gcursor, unsigned int* __restrict__ ebuf) {
  __shared__ __align__(16) unsigned char smem[64 * 296 * 2];  // 37,888 B
  const int tid = threadIdx.x;

  if (blockIdx.x >= KBG) {
    // ---- partition branch: one CH-edge chunk into NB buckets ----
    int* bcnt  = (int*)smem;                 // NB ints
    int* gbase = (int*)(smem + 5120);        // NB ints
    const int e0 = (blockIdx.x - KBG) * CH;
    const int e1 = (e0 + CH < E_NUM) ? (e0 + CH) : E_NUM;
    for (int i = tid; i < NB; i += 512) bcnt[i] = 0;
    __syncthreads();
    for (int e = e0 + tid; e < e1; e += 512)
      atomicAdd(&bcnt[dst_idx[e] >> 4], 1);
    __syncthreads();
    for (int i = tid; i < NB; i += 512) {
      const int cnt = bcnt[i];
      gbase[i] = (cnt > 0) ? atomicAdd(&gcursor[i], cnt) : 0;
      bcnt[i] = 0;  // reuse as rank counter
    }
    __syncthreads();
    for (int e = e0 + tid; e < e1; e += 512) {
      const int d = dst_idx[e];
      const int s = src_idx[e];
      const int b = d >> 4;
      const int r = atomicAdd(&bcnt[b], 1);
      const int pos = gbase[b] + r;
      if (pos < CAP)
        ebuf[(size_t)b * CAP + pos] = ((unsigned int)(d & 15) << 17) | (unsigned int)s;
    }
    return;
  }

  // ---- GEMM branch: two 64-row tiles, champion body per tile ----
  unsigned short (*lA)[296] = (unsigned short (*)[296])smem;
  unsigned short (*lC)[136] = (unsigned short (*)[136])smem;
  const int wave = tid >> 6;      // 0..7, each wave owns 16 output cols
  const int lane = tid & 63;
  const int quad = lane >> 4;
  const int l15 = lane & 15;
  const int col0 = wave * 16;
  const unsigned short* ebT = embedT + (size_t)(col0 + l15) * 256;

  // B fragments: tile-invariant, loaded once per block (L2-hot, 16B vec loads)
  bf16x8 fb[8];
#pragma unroll
  for (int kc = 0; kc < 8; ++kc)
    fb[kc] = *(const bf16x8*)(ebT + kc * 32 + quad * 8);

  for (int t = blockIdx.x; t < KB1; t += KBG) {
    const int row0 = t * 64;
    __syncthreads();   // previous tile's lC reads complete before lA overwrite

    // Stage [64 x 256] A tile, f32 -> bf16, 32B/thread/iter coalesced
#pragma unroll
    for (int i = 0; i < 4; ++i) {
      const int idx = i * 512 + tid;        // 0..2047
      const int row = idx >> 5;             // 0..63
      const int seg = idx & 31;             // 8-float segment
      // rows row0+row <= 100031 < N=120000: in-bounds (junk rows dropped at store)
      const float4* g = (const float4*)(sf + (size_t)(row0 + row) * 256 + seg * 8);
      const float4 v0 = g[0];
      const float4 v1 = g[1];
      uint4 pk;
      pk.x = f2bf2(v0.x, v0.y);
      pk.y = f2bf2(v0.z, v0.w);
      pk.z = f2bf2(v1.x, v1.y);
      pk.w = f2bf2(v1.z, v1.w);
      *(uint4*)&lA[row][seg * 8] = pk;
    }
    __syncthreads();

    f32x4 acc[4];
#pragma unroll
    for (int i = 0; i < 4; ++i) acc[i] = (f32x4){0.f, 0.f, 0.f, 0.f};

#pragma unroll
    for (int kc = 0; kc < 8; ++kc)
#pragma unroll
      for (int rt = 0; rt < 4; ++rt) {
        bf16x8 fa = *(const bf16x8*)&lA[rt * 16 + l15][kc * 32 + quad * 8];
        acc[rt] = __builtin_amdgcn_mfma_f32_16x16x32_bf16(fa, fb[kc], acc[rt], 0, 0, 0);
      }
    __syncthreads();  // done reading lA; smem becomes lC

    // acc -> LDS (row = rt*16+quad*4+reg, col = col0+l15), scaled by 1/xn
#pragma unroll
    for (int rt = 0; rt < 4; ++rt) {
#pragma unroll
      for (int reg = 0; reg < 4; ++reg) {
        const int row = rt * 16 + quad * 4 + reg;
        const float inv = __builtin_amdgcn_rcpf(xn[row0 + row]);
        lC[row][col0 + l15] = f2bf(acc[rt][reg] * inv);
      }
    }
    __syncthreads();

    // coalesced out: 2 passes x 512 thr x 16B = full 256B rows
#pragma unroll
    for (int p = 0; p < 2; ++p) {
      const int i = p * 512 + tid;
      const int row = i >> 4;
      const int seg = i & 15;
      const int gr = row0 + row;
      if (gr < S_NUM)
        *(uint4*)(xb + (size_t)gr * 128 + seg * 8) = *(const uint4*)&lC[row][seg * 8];
    }
  }
}

// K3 (fused sort + aggregate + output GEMM) — exact R13 champion version.
__launch_bounds__(512)
__global__ void k3_fused(const int* __restrict__ gcursor, const unsigned int* __restrict__ ebuf,
                         const unsigned short* __restrict__ xb,
                         const unsigned short* __restrict__ weightT,
                         float* __restrict__ out) {
  __shared__ unsigned int sls[CAP];       // sorted src list (5,120 B)
  __shared__ int hist[GT], scn[GT], cur[GT];
  __shared__ unsigned int Pu[GT][68];     // packed bf16 pairs, padded (4,352 B)
  const int b = blockIdx.x;
  const int tid = threadIdx.x;
  const int wave = tid >> 6, lane = tid & 63;
  const int quad = lane >> 4, l15 = lane & 15;

  int n = gcursor[b];
  if (n > CAP) n = CAP;
  const unsigned int* eb = ebuf + (size_t)b * CAP;

  // Phase A: counting-sort into LDS
  if (tid < GT) hist[tid] = 0;
  __syncthreads();
  for (int i = tid; i < n; i += 512) atomicAdd(&hist[eb[i] >> 17], 1);
  __syncthreads();
  if (tid == 0) {
    int run = 0;
#pragma unroll
    for (int i = 0; i < GT; ++i) { scn[i] = run; run += hist[i]; }
  }
  __syncthreads();
  if (tid < GT) cur[tid] = scn[tid];
  __syncthreads();
  for (int i = tid; i < n; i += 512) {
    const unsigned int e = eb[i];
    const int r = atomicAdd(&cur[e >> 17], 1);
    sls[r] = e & 0x1FFFFu;
  }
  __syncthreads();

  // Phase B: wave-per-target mean aggregation, paired-edge gather
  const int h = lane >> 5;          // 0: even local edges, 1: odd
  const int cq = lane & 31;         // col group: cols 4cq..4cq+3
#pragma unroll
  for (int rep = 0; rep < 2; ++rep) {
    const int tl = wave * 2 + rep;
    const int beg = scn[tl];
    const int c = hist[tl];
    float t0 = 0.f, t1 = 0.f, t2 = 0.f, t3 = 0.f;
    int e = 0;
    for (; e + 16 <= c; e += 16) {
      int s[8];
#pragma unroll
      for (int j = 0; j < 8; ++j) s[j] = (int)sls[beg + e + 2 * j + h];  // 2-addr LDS read
      uint2 v[8];
#pragma unroll
      for (int j = 0; j < 8; ++j)
        v[j] = *(const uint2*)(xb + (size_t)s[j] * 128 + 4 * cq);
#pragma unroll
      for (int j = 0; j < 8; ++j) {
        t0 += bflo(v[j].x); t1 += bfhi(v[j].x);
        t2 += bflo(v[j].y); t3 += bfhi(v[j].y);
      }
    }
    for (; e + 2 <= c; e += 2) {
      const int s0 = (int)sls[beg + e + h];
      const uint2 v0 = *(const uint2*)(xb + (size_t)s0 * 128 + 4 * cq);
      t0 += bflo(v0.x); t1 += bfhi(v0.x);
      t2 += bflo(v0.y); t3 += bfhi(v0.y);
    }
    if ((c & 1) && h == 0) {        // last odd edge belongs to the even group
      const int s0 = (int)sls[beg + c - 1];
      const uint2 v0 = *(const uint2*)(xb + (size_t)s0 * 128 + 4 * cq);
      t0 += bflo(v0.x); t1 += bfhi(v0.x);
      t2 += bflo(v0.y); t3 += bfhi(v0.y);
    }
    // combine even-group + odd-group (single cross-add, same as old a+b)
    t0 += __shfl_xor(t0, 32, 64);
    t1 += __shfl_xor(t1, 32, 64);
    t2 += __shfl_xor(t2, 32, 64);
    t3 += __shfl_xor(t3, 32, 64);
    const float inv = (c > 0) ? __builtin_amdgcn_rcpf((float)c) : 0.f;
    const unsigned int pk = h ? f2bf2(t2 * inv, t3 * inv) : f2bf2(t0 * inv, t1 * inv);
    Pu[tl][2 * cq + h] = pk;        // lane h=0 -> cols 4cq..+1, h=1 -> cols 4cq+2..+3
  }
  __syncthreads();

  // Phase C: out[b*16 .. b*16+15][:] = P @ W via one MFMA m-tile per wave-col
  const int ncol = wave * 16 + l15;
  const unsigned short* wT = weightT + (size_t)ncol * 128;
  bf16x8 wb[4];
#pragma unroll
  for (int kc = 0; kc < 4; ++kc)
    wb[kc] = *(const bf16x8*)(wT + kc * 32 + quad * 8);
  f32x4 o0 = (f32x4){0.f, 0.f, 0.f, 0.f};
#pragma unroll
  for (int kc = 0; kc < 4; ++kc) {
    bf16x8 p0 = *(const bf16x8*)((const unsigned short*)&Pu[l15][0] + kc * 32 + quad * 8);
    o0 = __builtin_amdgcn_mfma_f32_16x16x32_bf16(p0, wb[kc], o0, 0, 0, 0);
  }
#pragma unroll
  for (int reg = 0; reg < 4; ++reg)
    out[((size_t)b * GT + quad * 4 + reg) * 128 + ncol] = o0[reg];
}

extern "C" void kernel_launch(void* const* d_in, const int* in_sizes, int n_in,
                              void* d_out, int out_size, void* d_ws, size_t ws_size,
                              hipStream_t stream) {
  const float* sf      = (const float*)d_in[0];   // [N,256] f32 (only rows < S used)
  const int*   src_idx = (const int*)d_in[1];     // [E]
  const int*   dst_idx = (const int*)d_in[2];     // [E]
  /* d_in[3] range_list: unused */
  const float* xn      = (const float*)d_in[4];   // [N]
  const float* embed   = (const float*)d_in[5];   // [256,128]
  const float* weight  = (const float*)d_in[6];   // [128,128]
  float* out = (float*)d_out;                     // [T,128] f32

  // workspace layout (16B-aligned), total ~32.1 MB
  char* w = (char*)d_ws;
  unsigned short* xb      = (unsigned short*)(w);                // 25,600,000
  int* gcursor            = (int*)(w + 25600000);                // 8,192 (1250 used)
  unsigned int* ebuf      = (unsigned int*)(w + 25608192);       // 1250*1280*4 = 6,400,000
  unsigned short* embedT  = (unsigned short*)(w + 32008192);     // 128*256*2 = 65,536
  unsigned short* weightT = (unsigned short*)(w + 32073728);     // 128*128*2 = 32,768

  k0_prep<<<128, 256, 0, stream>>>(embed, weight, gcursor, embedT, weightT);
  k12_fused<<<KBG + KB2, 512, 0, stream>>>(sf, xn, embedT, xb, src_idx, dst_idx, gcursor, ebuf);
  k3_fused<<<NB, 512, 0, stream>>>(gcursor, ebuf, xb, weightT, out);
}

// Round 8
// 246.885 us; speedup vs baseline: 1.1533x; 1.0281x over previous
//
#include <hip/hip_runtime.h>
#include <cstdint>
#include <cstddef>

#define S_NUM 100000
#define T_NUM 20000
#define E_NUM 1000000

#define NB   1250     // buckets (T / GT)
#define GT   16       // targets per bucket
#define CAP  1280     // entries per bucket slot (mean 800, max ~950)
#define CH   4096     // edges per partition chunk
#define KB2  245      // k2-branch blocks (= chunks)
#define KB1  1563     // k1-branch blocks (= ceil(S/64))

typedef __bf16 bf16x8 __attribute__((ext_vector_type(8)));
typedef float f32x4 __attribute__((ext_vector_type(4)));

__device__ __forceinline__ unsigned short f2bf(float f) {
  unsigned int u = __float_as_uint(f);
  u += 0x7fffu + ((u >> 16) & 1u);   // round-to-nearest-even
  return (unsigned short)(u >> 16);
}
__device__ __forceinline__ unsigned int f2bf2(float lo, float hi) {
  return (unsigned int)f2bf(lo) | ((unsigned int)f2bf(hi) << 16);
}
__device__ __forceinline__ float bflo(unsigned int v) { return __uint_as_float(v << 16); }
__device__ __forceinline__ float bfhi(unsigned int v) { return __uint_as_float(v & 0xffff0000u); }

// K12: horizontally-fused kernel.
//   blocks [0, KB2):        edge partition into NB buckets (latency/atomic-bound)
//   blocks [KB2, KB2+KB1):  embed GEMM, 64-row tiles (MFMA/HBM-bound)
// 64-row tile => 37.9 KB LDS => 4 blocks/CU. Staging stride 296 shorts =
// 148 dw == 20 mod 32: measured 0-conflict fragment-read pattern.
__launch_bounds__(512)
__global__ void k12_fused(const float* __restrict__ sf, const float* __restrict__ xn,
                          const float* __restrict__ embed, unsigned short* __restrict__ xb,
                          const int* __restrict__ src_idx, const int* __restrict__ dst_idx,
                          int* __restrict__ gcursor, unsigned int* __restrict__ ebuf) {
  __shared__ __align__(16) unsigned char smem[64 * 296 * 2];  // 37,888 B
  const int tid = threadIdx.x;

  if (blockIdx.x < KB2) {
    // ---- k2 branch: partition one CH-edge chunk into NB buckets ----
    int* bcnt  = (int*)smem;                 // NB ints (5,000 B)
    int* gbase = (int*)(smem + 5120);        // NB ints
    const int e0 = blockIdx.x * CH;
    const int e1 = (e0 + CH < E_NUM) ? (e0 + CH) : E_NUM;
    for (int i = tid; i < NB; i += 512) bcnt[i] = 0;
    __syncthreads();
    for (int e = e0 + tid; e < e1; e += 512)
      atomicAdd(&bcnt[dst_idx[e] >> 4], 1);
    __syncthreads();
    for (int i = tid; i < NB; i += 512) {
      const int cnt = bcnt[i];
      gbase[i] = (cnt > 0) ? atomicAdd(&gcursor[i], cnt) : 0;
      bcnt[i] = 0;  // reuse as rank counter
    }
    __syncthreads();
    for (int e = e0 + tid; e < e1; e += 512) {
      const int d = dst_idx[e];
      const int s = src_idx[e];
      const int b = d >> 4;
      const int r = atomicAdd(&bcnt[b], 1);
      const int pos = gbase[b] + r;
      if (pos < CAP)
        ebuf[(size_t)b * CAP + pos] = ((unsigned int)(d & 15) << 17) | (unsigned int)s;
    }
    return;
  }

  // ---- k1 branch: xb[64-row tile] = bf16((sf @ embed) / xn) ----
  unsigned short (*lA)[296] = (unsigned short (*)[296])smem;
  unsigned short (*lC)[136] = (unsigned short (*)[136])smem;
  const int wave = tid >> 6;      // 0..7, each wave owns 16 output cols
  const int lane = tid & 63;
  const int quad = lane >> 4;
  const int l15 = lane & 15;
  const int row0 = (blockIdx.x - KB2) * 64;
  const int col0 = wave * 16;

  // B fragments straight from embed f32 (128 KB, L2-hot)
  bf16x8 fb[8];
#pragma unroll
  for (int kc = 0; kc < 8; ++kc) {
    union { unsigned short h[8]; bf16x8 v; } u;
#pragma unroll
    for (int j = 0; j < 8; ++j)
      u.h[j] = f2bf(embed[(size_t)(kc * 32 + quad * 8 + j) * 128 + col0 + l15]);
    fb[kc] = u.v;
  }

  // Stage [64 x 256] A tile, f32 -> bf16, 32B/thread/iter coalesced
#pragma unroll
  for (int i = 0; i < 4; ++i) {
    const int idx = i * 512 + tid;        // 0..2047
    const int row = idx >> 5;             // 0..63
    const int seg = idx & 31;             // 8-float segment
    // rows row0+row <= 100031 < N=120000: in-bounds (junk rows dropped at store)
    const float4* g = (const float4*)(sf + (size_t)(row0 + row) * 256 + seg * 8);
    const float4 v0 = g[0];
    const float4 v1 = g[1];
    uint4 pk;
    pk.x = f2bf2(v0.x, v0.y);
    pk.y = f2bf2(v0.z, v0.w);
    pk.z = f2bf2(v1.x, v1.y);
    pk.w = f2bf2(v1.z, v1.w);
    *(uint4*)&lA[row][seg * 8] = pk;
  }
  __syncthreads();

  f32x4 acc[4];
#pragma unroll
  for (int i = 0; i < 4; ++i) acc[i] = (f32x4){0.f, 0.f, 0.f, 0.f};

#pragma unroll
  for (int kc = 0; kc < 8; ++kc)
#pragma unroll
    for (int rt = 0; rt < 4; ++rt) {
      bf16x8 fa = *(const bf16x8*)&lA[rt * 16 + l15][kc * 32 + quad * 8];
      acc[rt] = __builtin_amdgcn_mfma_f32_16x16x32_bf16(fa, fb[kc], acc[rt], 0, 0, 0);
    }
  __syncthreads();  // done reading lA; smem becomes lC

  // acc -> LDS (row = rt*16+quad*4+reg, col = col0+l15), scaled by 1/xn
#pragma unroll
  for (int rt = 0; rt < 4; ++rt) {
#pragma unroll
    for (int reg = 0; reg < 4; ++reg) {
      const int row = rt * 16 + quad * 4 + reg;
      const float inv = __builtin_amdgcn_rcpf(xn[row0 + row]);
      lC[row][col0 + l15] = f2bf(acc[rt][reg] * inv);
    }
  }
  __syncthreads();

  // coalesced out: 2 passes x 512 thr x 16B = full 256B rows
#pragma unroll
  for (int p = 0; p < 2; ++p) {
    const int i = p * 512 + tid;
    const int row = i >> 4;
    const int seg = i & 15;
    const int gr = row0 + row;
    if (gr < S_NUM)
      *(uint4*)(xb + (size_t)gr * 128 + seg * 8) = *(const uint4*)&lC[row][seg * 8];
  }
}

// K3 (fused sort + aggregate + output GEMM). One block (512 thr, 8 waves)
// per 16-target bucket; 1250 blocks (~4.9/CU) for latency hiding.
__launch_bounds__(512)
__global__ void k3_fused(const int* __restrict__ gcursor, const unsigned int* __restrict__ ebuf,
                         const unsigned short* __restrict__ xb,
                         const float* __restrict__ weight,
                         float* __restrict__ out) {
  __shared__ unsigned int sls[CAP];       // sorted src list (5,120 B)
  __shared__ int hist[GT], scn[GT], cur[GT];
  __shared__ unsigned int Pu[GT][68];     // packed bf16 pairs, padded (4,352 B)
  const int b = blockIdx.x;
  const int tid = threadIdx.x;
  const int wave = tid >> 6, lane = tid & 63;
  const int quad = lane >> 4, l15 = lane & 15;

  int n = gcursor[b];
  if (n > CAP) n = CAP;
  const unsigned int* eb = ebuf + (size_t)b * CAP;

  // Phase A: counting-sort into LDS
  if (tid < GT) hist[tid] = 0;
  __syncthreads();
  for (int i = tid; i < n; i += 512) atomicAdd(&hist[eb[i] >> 17], 1);
  __syncthreads();
  if (tid == 0) {
    int run = 0;
#pragma unroll
    for (int i = 0; i < GT; ++i) { scn[i] = run; run += hist[i]; }
  }
  __syncthreads();
  if (tid < GT) cur[tid] = scn[tid];
  __syncthreads();
  for (int i = tid; i < n; i += 512) {
    const unsigned int e = eb[i];
    const int r = atomicAdd(&cur[e >> 17], 1);
    sls[r] = e & 0x1FFFFu;
  }
  __syncthreads();

  // Phase B: wave-per-target mean aggregation, 16-deep gather ILP
#pragma unroll
  for (int rep = 0; rep < 2; ++rep) {
    const int tl = wave * 2 + rep;
    const int beg = scn[tl];
    const int c = hist[tl];
    float a0 = 0.f, a1 = 0.f, b0 = 0.f, b1 = 0.f;
    int e = 0;
    for (; e + 16 <= c; e += 16) {
      int s[16];
#pragma unroll
      for (int j = 0; j < 16; ++j) s[j] = (int)sls[beg + e + j];  // LDS broadcast
      unsigned int v[16];
#pragma unroll
      for (int j = 0; j < 16; ++j)
        v[j] = *(const unsigned int*)(xb + (size_t)s[j] * 128 + 2 * lane);
#pragma unroll
      for (int j = 0; j < 16; j += 2) {
        a0 += bflo(v[j]);     a1 += bfhi(v[j]);
        b0 += bflo(v[j + 1]); b1 += bfhi(v[j + 1]);
      }
    }
    for (; e + 4 <= c; e += 4) {
      int s[4];
#pragma unroll
      for (int j = 0; j < 4; ++j) s[j] = (int)sls[beg + e + j];
      unsigned int v[4];
#pragma unroll
      for (int j = 0; j < 4; ++j)
        v[j] = *(const unsigned int*)(xb + (size_t)s[j] * 128 + 2 * lane);
      a0 += bflo(v[0]); a1 += bfhi(v[0]);
      b0 += bflo(v[1]); b1 += bfhi(v[1]);
      a0 += bflo(v[2]); a1 += bfhi(v[2]);
      b0 += bflo(v[3]); b1 += bfhi(v[3]);
    }
    for (; e < c; ++e) {
      const int s0 = (int)sls[beg + e];
      const unsigned int v0 = *(const unsigned int*)(xb + (size_t)s0 * 128 + 2 * lane);
      a0 += bflo(v0); a1 += bfhi(v0);
    }
    a0 += b0; a1 += b1;
    const float inv = (c > 0) ? __builtin_amdgcn_rcpf((float)c) : 0.f;
    Pu[tl][lane] = f2bf2(a0 * inv, a1 * inv);
  }
  __syncthreads();

  // Phase C: out[b*16 .. b*16+15][:] = P @ W via one MFMA m-tile per wave-col
  const int ncol = wave * 16 + l15;
  bf16x8 wb[4];
#pragma unroll
  for (int kc = 0; kc < 4; ++kc) {
    union { unsigned short h[8]; bf16x8 v; } u;
#pragma unroll
    for (int j = 0; j < 8; ++j)
      u.h[j] = f2bf(weight[(size_t)(kc * 32 + quad * 8 + j) * 128 + ncol]);
    wb[kc] = u.v;
  }
  f32x4 o0 = (f32x4){0.f, 0.f, 0.f, 0.f};
#pragma unroll
  for (int kc = 0; kc < 4; ++kc) {
    bf16x8 p0 = *(const bf16x8*)((const unsigned short*)&Pu[l15][0] + kc * 32 + quad * 8);
    o0 = __builtin_amdgcn_mfma_f32_16x16x32_bf16(p0, wb[kc], o0, 0, 0, 0);
  }
#pragma unroll
  for (int reg = 0; reg < 4; ++reg)
    out[((size_t)b * GT + quad * 4 + reg) * 128 + ncol] = o0[reg];
}

extern "C" void kernel_launch(void* const* d_in, const int* in_sizes, int n_in,
                              void* d_out, int out_size, void* d_ws, size_t ws_size,
                              hipStream_t stream) {
  const float* sf      = (const float*)d_in[0];   // [N,256] f32 (only rows < S used)
  const int*   src_idx = (const int*)d_in[1];     // [E]
  const int*   dst_idx = (const int*)d_in[2];     // [E]
  /* d_in[3] range_list: unused */
  const float* xn      = (const float*)d_in[4];   // [N]
  const float* embed   = (const float*)d_in[5];   // [256,128]
  const float* weight  = (const float*)d_in[6];   // [128,128]
  float* out = (float*)d_out;                     // [T,128] f32

  // workspace layout (16B-aligned), total ~32.0 MB
  char* w = (char*)d_ws;
  unsigned short* xb = (unsigned short*)(w);            // 25,600,000
  int* gcursor       = (int*)(w + 25600000);            // 8,192 (1250 used)
  unsigned int* ebuf = (unsigned int*)(w + 25608192);   // 1250*1280*4 = 6,400,000

  hipMemsetAsync(gcursor, 0, 8192, stream);
  k12_fused<<<KB2 + KB1, 512, 0, stream>>>(sf, xn, embed, xb, src_idx, dst_idx, gcursor, ebuf);
  k3_fused<<<NB, 512, 0, stream>>>(gcursor, ebuf, xb, weight, out);
}